// Round 1
// baseline (152.192 us; speedup 1.0000x reference)
//
#include <hip/hip_runtime.h>

// Radon3D loss on MI355X.
// Geometry constants (D=H=W=64 volume, 120 angles over [0,120] deg):
//   L = ceil(sqrt(64^2+64^2)) = 91, pad top=left=13.
//   Sample coords: ix(i,j) = 45*c*linj + 32 + 45*s - s*i
//                  iy(i,j) = 45*s*linj + 32 - 45*c + c*i
//   (linj = j/45 - 1; unit steps in i because 0.5*(L-1) cancels linspace step)
#define DD 64
#define NA 120
#define NS 64
#define LL 91
#define PS 67       // padded canvas: indices 0..66 valid after clamp to [-1,64]
#define PSTR 68     // row stride (in float2)
#define NBLK (NS * NA)

__global__ __launch_bounds__(256) void radon_loss_kernel(
    const float* __restrict__ vout, const float* __restrict__ vgt,
    float* __restrict__ partial)
{
    __shared__ float2 P[PS * PSTR];   // (out, gt) interleaved, zero border
    __shared__ float2 colsum[LL];     // half-0 partial (acc_o, acc_g) per column
    __shared__ float wsum[4];

    const int bid = blockIdx.x;
    const int s = bid / NA;
    const int a = bid - s * NA;
    const int t = threadIdx.x;

    // 1) zero the padded canvas
    for (int idx = t; idx < PS * PSTR; idx += 256)
        P[idx] = make_float2(0.f, 0.f);
    __syncthreads();

    // 2) load slice s of both volumes into the interior.
    //    im[d][w] = vol[0,0,d,s,w] -> flat d*4096 + s*64 + w
    for (int idx = t; idx < DD * DD; idx += 256) {
        const int d = idx >> 6, w = idx & 63;
        const int g = d * 4096 + s * 64 + w;
        P[(d + 1) * PSTR + (w + 1)] = make_float2(vout[g], vgt[g]);
    }
    __syncthreads();

    // 3) projection: thread = (column j, i-half)
    const float theta = (float)a * (float)(3.14159265358979323846 * 120.0 / 119.0 / 180.0);
    const float c = cosf(theta), sn = sinf(theta);

    const int j = t & 127;
    const int half = t >> 7;
    float acc_o = 0.f, acc_g = 0.f;

    if (j < LL) {
        const float linj = fmaf((float)j, 2.0f / 90.0f, -1.0f);
        const float bx = fmaf(c,  linj, 1.0f) * 45.0f - 13.0f + 45.0f * sn;
        const float by = fmaf(sn, linj, 1.0f) * 45.0f - 13.0f - 45.0f * c;
        const int i0 = half ? 46 : 0;
        const int i1 = half ? LL : 46;
        for (int i = i0; i < i1; ++i) {
            float x = fmaf(-(float)i, sn, bx);
            float y = fmaf( (float)i, c,  by);
            // clamp to [-1,64]: out-of-support samples hit the zero border
            // with zero weight -> exactly mode='constant', cval=0
            x = fminf(fmaxf(x, -1.0f), 64.0f);
            y = fminf(fmaxf(y, -1.0f), 64.0f);
            const float fx = floorf(x), fy = floorf(y);
            const float wx = x - fx,   wy = y - fy;
            const int x0 = (int)fx + 1, y0 = (int)fy + 1;
            const float2* p = &P[y0 * PSTR + x0];
            const float2 v00 = p[0], v01 = p[1];
            const float2 v10 = p[PSTR], v11 = p[PSTR + 1];
            const float to = fmaf(wx, v01.x - v00.x, v00.x);
            const float bo = fmaf(wx, v11.x - v10.x, v10.x);
            acc_o += fmaf(wy, bo - to, to);
            const float tg = fmaf(wx, v01.y - v00.y, v00.y);
            const float bg = fmaf(wx, v11.y - v10.y, v10.y);
            acc_g += fmaf(wy, bg - tg, tg);
        }
    }

    // 4) combine i-halves per column, THEN abs (abs must see the full i-sum)
    if (half == 0 && j < LL) colsum[j] = make_float2(acc_o, acc_g);
    __syncthreads();
    float val = 0.f;
    if (half == 1 && j < LL) {
        const float2 cs = colsum[j];
        val = fabsf((cs.x + acc_o) - (cs.y + acc_g));
    }

    // 5) block reduction (4 waves)
    #pragma unroll
    for (int off = 32; off > 0; off >>= 1)
        val += __shfl_down(val, off);
    const int wave = t >> 6, lane = t & 63;
    if (lane == 0) wsum[wave] = val;
    __syncthreads();
    if (t == 0)
        partial[bid] = wsum[0] + wsum[1] + wsum[2] + wsum[3];
}

__global__ __launch_bounds__(256) void finalize_kernel(
    const float* __restrict__ partial, float* __restrict__ out)
{
    __shared__ float wsum[4];
    float v = 0.f;
    for (int i = threadIdx.x; i < NBLK; i += 256) v += partial[i];
    #pragma unroll
    for (int off = 32; off > 0; off >>= 1)
        v += __shfl_down(v, off);
    const int wave = threadIdx.x >> 6, lane = threadIdx.x & 63;
    if (lane == 0) wsum[wave] = v;
    __syncthreads();
    if (threadIdx.x == 0)
        out[0] = (wsum[0] + wsum[1] + wsum[2] + wsum[3]) * (1.0f / (float)(NA * LL));
}

extern "C" void kernel_launch(void* const* d_in, const int* in_sizes, int n_in,
                              void* d_out, int out_size, void* d_ws, size_t ws_size,
                              hipStream_t stream) {
    const float* vout = (const float*)d_in[0];
    const float* vgt  = (const float*)d_in[1];
    float* out = (float*)d_out;
    float* partial = (float*)d_ws;   // NBLK floats = 30 KB

    radon_loss_kernel<<<NBLK, 256, 0, stream>>>(vout, vgt, partial);
    finalize_kernel<<<1, 256, 0, stream>>>(partial, out);
}

// Round 2
// 132.635 us; speedup vs baseline: 1.1475x; 1.1475x over previous
//
#include <hip/hip_runtime.h>
#include <hip/hip_fp16.h>

// Radon3D loss on MI355X.
// Geometry (D=H=W=64, 120 angles over [0,120] deg):
//   L = 91, pad top=left=13.
//   ix(i,j) = 45*c*linj + 32 + 45*s - s*i,  iy(i,j) = 45*s*linj + 32 - 45*c + c*i
//   (unit steps in i: the 0.5*(L-1) unnormalization cancels the linspace step)
// Canvas: half2 (out,gt) packed, zero border, clamp coords to [-1,64] so
// out-of-support samples hit the zero border with zero weight (== cval=0).
// Row stride 69 (odd) -> bank-conflict-free for any sample-line direction.
#define DD 64
#define NA 120
#define NS 64
#define LL 91
#define PS 67
#define PSTR 69      // odd word stride: 69 mod 32 = 5 -> no structured conflicts
#define NBLK (NS * NA)

__global__ __launch_bounds__(256, 8) void radon_loss_kernel(
    const float* __restrict__ vout, const float* __restrict__ vgt,
    float* __restrict__ partial)
{
    __shared__ __half2 P[PS * PSTR];  // 4623 * 4 B = 18.5 KB
    __shared__ float2 colsum[LL];
    __shared__ float wsum[4];

    const int bid = blockIdx.x;
    const int s = bid / NA;
    const int a = bid - s * NA;
    const int t = threadIdx.x;

    // 1) zero the padded canvas
    for (int idx = t; idx < PS * PSTR; idx += 256)
        P[idx] = __floats2half2_rn(0.f, 0.f);
    __syncthreads();

    // 2) load slice s of both volumes: im[d][w] = vol[0,0,d,s,w]
    for (int idx = t; idx < DD * DD; idx += 256) {
        const int d = idx >> 6, w = idx & 63;
        const int g = d * 4096 + s * 64 + w;
        P[(d + 1) * PSTR + (w + 1)] = __floats2half2_rn(vout[g], vgt[g]);
    }
    __syncthreads();

    // 3) projection: thread = (column j, i-half)
    const float theta = (float)a * (float)(3.14159265358979323846 * 120.0 / 119.0 / 180.0);
    const float c = cosf(theta), sn = sinf(theta);

    const int j = t & 127;
    const int half = t >> 7;
    float acc_o = 0.f, acc_g = 0.f;

    if (j < LL) {
        const float linj = fmaf((float)j, 2.0f / 90.0f, -1.0f);
        const float bx = fmaf(c,  linj, 1.0f) * 45.0f - 13.0f + 45.0f * sn;
        const float by = fmaf(sn, linj, 1.0f) * 45.0f - 13.0f - 45.0f * c;
        const int i0 = half ? 46 : 0;
        const int i1 = half ? LL : 46;
        float x = fmaf(-(float)i0, sn, bx);
        float y = fmaf( (float)i0, c,  by);
        for (int i = i0; i < i1; ++i) {
            const float xc = fminf(fmaxf(x, -1.0f), 64.0f);
            const float yc = fminf(fmaxf(y, -1.0f), 64.0f);
            const float fx = floorf(xc), fy = floorf(yc);
            const float wx = xc - fx,   wy = yc - fy;
            // base index (fy+1)*69 + (fx+1) = fma(fy,69,fx) + 70, exact small ints
            const int ia = (int)fmaf(fy, 69.0f, fx);
            const __half2* p = &P[ia + 70];
            const __half2 v00 = p[0],    v01 = p[1];
            const __half2 v10 = p[PSTR], v11 = p[PSTR + 1];
            const __half2 wx2 = __float2half2_rn(wx);
            const __half2 wy2 = __float2half2_rn(wy);
            const __half2 top = __hfma2(wx2, __hsub2(v01, v00), v00);
            const __half2 bot = __hfma2(wx2, __hsub2(v11, v10), v10);
            const __half2 r   = __hfma2(wy2, __hsub2(bot, top), top);
            acc_o += __low2float(r);
            acc_g += __high2float(r);
            x -= sn;
            y += c;
        }
    }

    // 4) combine i-halves per column, THEN abs (abs needs the full i-sum)
    if (half == 0 && j < LL) colsum[j] = make_float2(acc_o, acc_g);
    __syncthreads();
    float val = 0.f;
    if (half == 1 && j < LL) {
        const float2 cs = colsum[j];
        val = fabsf((cs.x + acc_o) - (cs.y + acc_g));
    }

    // 5) block reduction
    #pragma unroll
    for (int off = 32; off > 0; off >>= 1)
        val += __shfl_down(val, off);
    const int wave = t >> 6, lane = t & 63;
    if (lane == 0) wsum[wave] = val;
    __syncthreads();
    if (t == 0)
        partial[bid] = wsum[0] + wsum[1] + wsum[2] + wsum[3];
}

__global__ __launch_bounds__(256) void finalize_kernel(
    const float* __restrict__ partial, float* __restrict__ out)
{
    __shared__ float wsum[4];
    float v = 0.f;
    for (int i = threadIdx.x; i < NBLK; i += 256) v += partial[i];
    #pragma unroll
    for (int off = 32; off > 0; off >>= 1)
        v += __shfl_down(v, off);
    const int wave = threadIdx.x >> 6, lane = threadIdx.x & 63;
    if (lane == 0) wsum[wave] = v;
    __syncthreads();
    if (threadIdx.x == 0)
        out[0] = (wsum[0] + wsum[1] + wsum[2] + wsum[3]) * (1.0f / (float)(NA * LL));
}

extern "C" void kernel_launch(void* const* d_in, const int* in_sizes, int n_in,
                              void* d_out, int out_size, void* d_ws, size_t ws_size,
                              hipStream_t stream) {
    const float* vout = (const float*)d_in[0];
    const float* vgt  = (const float*)d_in[1];
    float* out = (float*)d_out;
    float* partial = (float*)d_ws;   // NBLK floats = 30 KB

    radon_loss_kernel<<<NBLK, 256, 0, stream>>>(vout, vgt, partial);
    finalize_kernel<<<1, 256, 0, stream>>>(partial, out);
}

// Round 3
// 116.878 us; speedup vs baseline: 1.3021x; 1.1348x over previous
//
#include <hip/hip_runtime.h>
#include <hip/hip_fp16.h>

// Radon3D loss on MI355X — 2 slices per block.
// Geometry (D=H=W=64, 120 angles over [0,120] deg):
//   L = 91, pad top=left=13.
//   ix(i,j) = 45*c*linj + 32 + 45*s - s*i,  iy(i,j) = 45*s*linj + 32 - 45*c + c*i
//   (unit steps in i: the 0.5*(L-1) unnormalization cancels the linspace step)
// Canvas cell = 8 B: [half2(out,gt) slice s0 | half2(out,gt) slice s1].
// Coordinate math is slice-independent -> amortized over 2 slices.
// Corners (0,+1) and (+69,+70) merge into 2x ds_read2_b64.
// Clamp coords to [-1,64]: out-of-support samples hit the zero border with
// zero weight == map_coordinates mode='constant', cval=0.
#define DD 64
#define NA 120
#define NS 64
#define LL 91
#define PS 67
#define PSTR 69          // odd cell stride -> no structured bank conflicts
#define NCELL (PS * PSTR)
#define NBLK2 ((NS / 2) * NA)

__global__ __launch_bounds__(256, 4) void radon_loss_kernel(
    const float* __restrict__ vout, const float* __restrict__ vgt,
    float* __restrict__ partial)
{
    __shared__ uint2 P[NCELL];        // 4623 * 8 B = 37.0 KB
    __shared__ float4 colsum[LL];     // half-0 partials (o0,g0,o1,g1)
    __shared__ float wsum[4];

    const int bid = blockIdx.x;
    const int sp = bid / NA;          // slice pair 0..31
    const int a = bid - sp * NA;
    const int s0 = sp * 2;
    const int t = threadIdx.x;

    // 1) zero the padded canvas
    for (int idx = t; idx < NCELL; idx += 256)
        P[idx] = make_uint2(0u, 0u);
    __syncthreads();

    // 2) stage slices s0, s0+1 of both volumes: im[d][w] = vol[0,0,d,s,w]
    for (int idx = t; idx < DD * DD; idx += 256) {
        const int d = idx >> 6, w = idx & 63;
        const int g0 = d * 4096 + s0 * 64 + w;   // slice s0
        const int g1 = g0 + 64;                  // slice s0+1
        const __half2 c0 = __floats2half2_rn(vout[g0], vgt[g0]);
        const __half2 c1 = __floats2half2_rn(vout[g1], vgt[g1]);
        uint2 cell;
        cell.x = *(const unsigned int*)&c0;
        cell.y = *(const unsigned int*)&c1;
        P[(d + 1) * PSTR + (w + 1)] = cell;
    }
    __syncthreads();

    // 3) projection: thread = (column j, i-half); both slices per thread
    const float theta = (float)a * (float)(3.14159265358979323846 * 120.0 / 119.0 / 180.0);
    const float c = cosf(theta), sn = sinf(theta);

    const int j = t & 127;
    const int half = t >> 7;
    float acc_o0 = 0.f, acc_g0 = 0.f, acc_o1 = 0.f, acc_g1 = 0.f;

    if (j < LL) {
        const float linj = fmaf((float)j, 2.0f / 90.0f, -1.0f);
        const float bx = fmaf(c,  linj, 1.0f) * 45.0f - 13.0f + 45.0f * sn;
        const float by = fmaf(sn, linj, 1.0f) * 45.0f - 13.0f - 45.0f * c;
        const int i0 = half ? 46 : 0;
        const int i1 = half ? LL : 46;
        float x = fmaf(-(float)i0, sn, bx);
        float y = fmaf( (float)i0, c,  by);
        for (int i = i0; i < i1; ++i) {
            const float xc = fminf(fmaxf(x, -1.0f), 64.0f);
            const float yc = fminf(fmaxf(y, -1.0f), 64.0f);
            const float fx = floorf(xc), fy = floorf(yc);
            const float wx = xc - fx,   wy = yc - fy;
            const int ci = (int)fmaf(fy, 69.0f, fx) + 70;   // exact small ints
            const uint2 q00 = P[ci],       q01 = P[ci + 1];
            const uint2 q10 = P[ci + 69],  q11 = P[ci + 70];
            const __half2 wx2 = __float2half2_rn(wx);
            const __half2 wy2 = __float2half2_rn(wy);
            // slice-pair A (cell.x)
            const __half2 a00 = *(const __half2*)&q00.x, a01 = *(const __half2*)&q01.x;
            const __half2 a10 = *(const __half2*)&q10.x, a11 = *(const __half2*)&q11.x;
            const __half2 ta = __hfma2(wx2, __hsub2(a01, a00), a00);
            const __half2 ba = __hfma2(wx2, __hsub2(a11, a10), a10);
            const __half2 ra = __hfma2(wy2, __hsub2(ba, ta), ta);
            // slice-pair B (cell.y)
            const __half2 b00 = *(const __half2*)&q00.y, b01 = *(const __half2*)&q01.y;
            const __half2 b10 = *(const __half2*)&q10.y, b11 = *(const __half2*)&q11.y;
            const __half2 tb = __hfma2(wx2, __hsub2(b01, b00), b00);
            const __half2 bb = __hfma2(wx2, __hsub2(b11, b10), b10);
            const __half2 rb = __hfma2(wy2, __hsub2(bb, tb), tb);
            acc_o0 += __low2float(ra);  acc_g0 += __high2float(ra);
            acc_o1 += __low2float(rb);  acc_g1 += __high2float(rb);
            x -= sn;
            y += c;
        }
    }

    // 4) combine i-halves per column, THEN abs (abs needs the full i-sum)
    if (half == 0 && j < LL) colsum[j] = make_float4(acc_o0, acc_g0, acc_o1, acc_g1);
    __syncthreads();
    float val = 0.f;
    if (half == 1 && j < LL) {
        const float4 cs = colsum[j];
        val = fabsf((cs.x + acc_o0) - (cs.y + acc_g0))
            + fabsf((cs.z + acc_o1) - (cs.w + acc_g1));
    }

    // 5) block reduction
    #pragma unroll
    for (int off = 32; off > 0; off >>= 1)
        val += __shfl_down(val, off);
    const int wave = t >> 6, lane = t & 63;
    if (lane == 0) wsum[wave] = val;
    __syncthreads();
    if (t == 0)
        partial[bid] = wsum[0] + wsum[1] + wsum[2] + wsum[3];
}

__global__ __launch_bounds__(256) void finalize_kernel(
    const float* __restrict__ partial, float* __restrict__ out)
{
    __shared__ float wsum[4];
    float v = 0.f;
    for (int i = threadIdx.x; i < NBLK2; i += 256) v += partial[i];
    #pragma unroll
    for (int off = 32; off > 0; off >>= 1)
        v += __shfl_down(v, off);
    const int wave = threadIdx.x >> 6, lane = threadIdx.x & 63;
    if (lane == 0) wsum[wave] = v;
    __syncthreads();
    if (threadIdx.x == 0)
        out[0] = (wsum[0] + wsum[1] + wsum[2] + wsum[3]) * (1.0f / (float)(NA * LL));
}

extern "C" void kernel_launch(void* const* d_in, const int* in_sizes, int n_in,
                              void* d_out, int out_size, void* d_ws, size_t ws_size,
                              hipStream_t stream) {
    const float* vout = (const float*)d_in[0];
    const float* vgt  = (const float*)d_in[1];
    float* out = (float*)d_out;
    float* partial = (float*)d_ws;   // NBLK2 floats = 15 KB

    radon_loss_kernel<<<NBLK2, 256, 0, stream>>>(vout, vgt, partial);
    finalize_kernel<<<1, 256, 0, stream>>>(partial, out);
}

// Round 4
// 84.040 us; speedup vs baseline: 1.8110x; 1.3908x over previous
//
#include <hip/hip_runtime.h>
#include <hip/hip_fp16.h>

// Radon3D loss on MI355X — project the DIFFERENCE volume (radon is linear!).
// Geometry (D=H=W=64, 120 angles over [0,120] deg): L=91, pad top=left=13.
//   ix(i,j) = 45*c*linj + 32 + 45*s - s*i,  iy(i,j) = 45*s*linj + 32 - 45*c + c*i
//   (unit steps in i: the 0.5*(L-1) unnormalization cancels the linspace step)
// Canvas cell = uint2 = 4 x fp16 diff (out-gt) for 4 slices; zero border;
// clamp coords to [-1,64] so out-of-support samples hit the zero border with
// zero weight == map_coordinates mode='constant', cval=0.
// Block = 384 thr: 4 angles x 96 j-lanes (91 active -> 95% lane util).
#define DD 64
#define NA 120
#define NS 64
#define LL 91
#define PS 67
#define PSTR 69               // odd cell stride -> no structured bank conflicts
#define NCELL (PS * PSTR)     // 4623 cells * 8 B = 37.0 KB
#define NSL 4                 // slices per block
#define NANG 4                // angles per block
#define JT 96                 // j-lanes per angle
#define NTHR (NANG * JT)      // 384
#define NBLKS ((NS / NSL) * (NA / NANG))   // 16 * 30 = 480

static __device__ __forceinline__ __half2 u2h(unsigned int u) {
    union { unsigned int u; __half2 h; } v; v.u = u; return v.h;
}

__global__ __launch_bounds__(NTHR, 6) void radon_loss_kernel(
    const float* __restrict__ vout, const float* __restrict__ vgt,
    float* __restrict__ out)
{
    __shared__ uint2 P[NCELL];
    __shared__ float wsum[NTHR / 64];

    const int bid = blockIdx.x;
    const int sp = bid / (NA / NANG);          // slice group 0..15
    const int ap = bid - sp * (NA / NANG);     // angle group 0..29
    const int s0 = sp * NSL;
    const int t = threadIdx.x;

    // 1) zero the padded canvas
    for (int idx = t; idx < NCELL; idx += NTHR)
        P[idx] = make_uint2(0u, 0u);
    __syncthreads();

    // 2) stage fp16 diffs of 4 slices: im_s[d][w] = vol[0,0,d,s,w]
    for (int idx = t; idx < DD * DD; idx += NTHR) {
        const int d = idx >> 6, w = idx & 63;
        const int g = d * 4096 + s0 * 64 + w;
        const float d0 = vout[g]       - vgt[g];
        const float d1 = vout[g + 64]  - vgt[g + 64];
        const float d2 = vout[g + 128] - vgt[g + 128];
        const float d3 = vout[g + 192] - vgt[g + 192];
        const __half2 lo = __floats2half2_rn(d0, d1);
        const __half2 hi = __floats2half2_rn(d2, d3);
        uint2 cell;
        cell.x = *(const unsigned int*)&lo;
        cell.y = *(const unsigned int*)&hi;
        P[(d + 1) * PSTR + (w + 1)] = cell;
    }
    __syncthreads();

    // 3) projection: thread = (angle slot, column j); full i-range per thread
    const int ja = t / JT;
    const int j  = t - ja * JT;
    const int a  = ap * NANG + ja;
    const float theta = (float)a * (float)(3.14159265358979323846 * 120.0 / 119.0 / 180.0);
    const float c = cosf(theta), sn = sinf(theta);

    float val = 0.f;
    if (j < LL) {
        const float linj = fmaf((float)j, 2.0f / 90.0f, -1.0f);
        float x = fmaf(c,  linj, 1.0f) * 45.0f - 13.0f + 45.0f * sn;
        float y = fmaf(sn, linj, 1.0f) * 45.0f - 13.0f - 45.0f * c;
        __half2 acc_lo = __floats2half2_rn(0.f, 0.f);
        __half2 acc_hi = acc_lo;
        for (int i = 0; i < LL; ++i) {
            const float xc = fminf(fmaxf(x, -1.0f), 64.0f);
            const float yc = fminf(fmaxf(y, -1.0f), 64.0f);
            const float fx = floorf(xc), fy = floorf(yc);
            const __half2 wx2 = __float2half2_rn(xc - fx);
            const __half2 wy2 = __float2half2_rn(yc - fy);
            const int ci = (int)fmaf(fy, 69.0f, fx) + 70;   // exact small ints
            const uint2 q00 = P[ci],      q01 = P[ci + 1];
            const uint2 q10 = P[ci + 69], q11 = P[ci + 70];
            // slices s0,s0+1 (cell.x)
            const __half2 t0 = __hfma2(wx2, __hsub2(u2h(q01.x), u2h(q00.x)), u2h(q00.x));
            const __half2 b0 = __hfma2(wx2, __hsub2(u2h(q11.x), u2h(q10.x)), u2h(q10.x));
            acc_lo = __hadd2(acc_lo, __hfma2(wy2, __hsub2(b0, t0), t0));
            // slices s0+2,s0+3 (cell.y)
            const __half2 t1 = __hfma2(wx2, __hsub2(u2h(q01.y), u2h(q00.y)), u2h(q00.y));
            const __half2 b1 = __hfma2(wx2, __hsub2(u2h(q11.y), u2h(q10.y)), u2h(q10.y));
            acc_hi = __hadd2(acc_hi, __hfma2(wy2, __hsub2(b1, t1), t1));
            x -= sn;
            y += c;
        }
        const float2 alo = __half22float2(acc_lo);
        const float2 ahi = __half22float2(acc_hi);
        val = fabsf(alo.x) + fabsf(alo.y) + fabsf(ahi.x) + fabsf(ahi.y);
    }

    // 4) block reduction + one scaled atomic per block
    #pragma unroll
    for (int off = 32; off > 0; off >>= 1)
        val += __shfl_down(val, off);
    const int wave = t >> 6, lane = t & 63;
    if (lane == 0) wsum[wave] = val;
    __syncthreads();
    if (t == 0) {
        float v = 0.f;
        #pragma unroll
        for (int wv = 0; wv < NTHR / 64; ++wv) v += wsum[wv];
        atomicAdd(out, v * (1.0f / (float)(NA * LL)));
    }
}

extern "C" void kernel_launch(void* const* d_in, const int* in_sizes, int n_in,
                              void* d_out, int out_size, void* d_ws, size_t ws_size,
                              hipStream_t stream) {
    const float* vout = (const float*)d_in[0];
    const float* vgt  = (const float*)d_in[1];
    float* out = (float*)d_out;

    hipMemsetAsync(out, 0, sizeof(float), stream);
    radon_loss_kernel<<<NBLKS, NTHR, 0, stream>>>(vout, vgt, out);
}